// Round 12
// baseline (717.853 us; speedup 1.0000x reference)
//
#include <hip/hip_runtime.h>

#define DEV __device__ __forceinline__

typedef float f32x4 __attribute__((ext_vector_type(4)));
typedef short s16x8 __attribute__((ext_vector_type(8)));
typedef unsigned short u16;
typedef u16 u16x4 __attribute__((ext_vector_type(4)));
typedef u16 u16x8 __attribute__((ext_vector_type(8)));
typedef unsigned int u32x4 __attribute__((ext_vector_type(4)));

constexpr int Bb = 16, Tt = 64, Ss = 128, Dd = 512, Vv = 32000, FD = 2048;

DEV u16 f2bf(float x) {                       // RNE f32 -> bf16
  unsigned u = __builtin_bit_cast(unsigned, x);
  u = u + 0x7fffu + ((u >> 16) & 1u);
  return (u16)(u >> 16);
}
DEV float bf2f(u16 h) { unsigned u = ((unsigned)h) << 16; return __builtin_bit_cast(float, u); }
DEV float sigm(float x) { return 1.f / (1.f + __expf(-x)); }
DEV float ftanh(float x) {
  x = fminf(15.f, fmaxf(-15.f, x));
  float e = __expf(2.f * x);
  return (e - 1.f) / (e + 1.f);
}

DEV void cvt_plain_one(const float* __restrict__ in, u16* __restrict__ out, int i) {
  float4 v = reinterpret_cast<const float4*>(in)[i];
  u16x4 o;
  o.x = f2bf(v.x); o.y = f2bf(v.y); o.z = f2bf(v.z); o.w = f2bf(v.w);
  reinterpret_cast<u16x4*>(out)[i] = o;
}

DEV void cvt_split_one(const float* __restrict__ in, u16* __restrict__ hi,
                       u16* __restrict__ lo, int i) {
  float4 v = reinterpret_cast<const float4*>(in)[i];
  u16x4 oh, ol;
  float vv[4] = {v.x, v.y, v.z, v.w};
#pragma unroll
  for (int j = 0; j < 4; ++j) {
    u16 h = f2bf(vv[j]);
    oh[j] = h;
    ol[j] = f2bf(vv[j] - bf2f(h));
  }
  reinterpret_cast<u16x4*>(hi)[i] = oh;
  reinterpret_cast<u16x4*>(lo)[i] = ol;
}

// ---------------- fused prologue: embed + preh + bsum + (Wih, enc, Whw) converts -----
__global__ void k_pre(const int* __restrict__ words, const float* __restrict__ emb,
                      u16* __restrict__ xb,
                      const float* __restrict__ pre, unsigned* __restrict__ hp0,
                      const float* __restrict__ bi, const float* __restrict__ bh,
                      float* __restrict__ bsum,
                      const float* __restrict__ Wih, u16* __restrict__ Wih_bf,
                      const float* __restrict__ enc, u16* __restrict__ ench,
                      u16* __restrict__ encl,
                      const float* __restrict__ Whw, u16* __restrict__ whh,
                      u16* __restrict__ whl) {
  int blk = blockIdx.x, tid = threadIdx.x;
  if (blk < Bb * Tt) {
    int row = words[blk];
    int d = tid * 2;
    float2 v = *reinterpret_cast<const float2*>(&emb[(size_t)row * Dd + d]);
    xb[(size_t)blk * Dd + d] = f2bf(v.x);
    xb[(size_t)blk * Dd + d + 1] = f2bf(v.y);
  } else if (blk < Bb * Tt + 32) {
    int i = (blk - Bb * Tt) * 256 + tid;  // Bb*Dd = 8192
    float v = pre[i];
    u16 h = f2bf(v);
    u16 l = f2bf(v - bf2f(h));
    hp0[i] = (unsigned)h | ((unsigned)l << 16);
  } else if (blk < Bb * Tt + 40) {
    int i = (blk - Bb * Tt - 32) * 256 + tid;  // FD = 2048
    bsum[i] = bi[i] + bh[i];
  } else {
    const int n0 = FD * Dd / 4, n1 = Bb * Ss * Dd / 4, n2 = Dd * Dd / 4;
    int total = n0 + n1 + n2;
    int i = (blk - (Bb * Tt + 40)) * 256 + tid;
    int st = 256 * 256;
    for (; i < total; i += st) {
      if (i < n0) cvt_plain_one(Wih, Wih_bf, i);
      else if (i < n0 + n1) cvt_split_one(enc, ench, encl, i - n0);
      else cvt_split_one(Whw, whh, whl, i - n0 - n1);
    }
  }
}

// ---------------- bf16 GEMM body: C[M,N] = A[M,K] @ B[N,K]^T (+bias) ----------------
// 128x128 tile, BK=32, 4 waves each owning a 64x64 quadrant (4x4 frags of 16x16x32 MFMA).
// TERMS==3: split-bf16 A=(Ah+Al), B=(Bh+Bl); computes Ah*Bh + Ah*Bl + Al*Bh fused.
template <bool BIAS, bool OUTBF, int TERMS>
DEV void gemm_body(u16* ls, int tile, int tid,
                   const u16* __restrict__ A, const u16* __restrict__ Al,
                   const u16* __restrict__ Bm, const u16* __restrict__ Bl,
                   float* __restrict__ Cf, u16* __restrict__ Cb,
                   const float* __restrict__ bias, int M, int N, int K) {
  u16* lsA = ls;
  u16* lsB = ls + 128 * 32;
  u16* lsAl = ls + 2 * 128 * 32;
  u16* lsBl = ls + 3 * 128 * 32;
  const int mt = M >> 7;
  const int tm = (tile % mt) << 7;
  const int tn = (tile / mt) << 7;
  const int wave = tid >> 6, lane = tid & 63;
  const int wr = wave >> 1, wc = wave & 1;
  f32x4 acc[4][4];
#pragma unroll
  for (int i = 0; i < 4; ++i)
#pragma unroll
    for (int j = 0; j < 4; ++j) acc[i][j] = (f32x4){0.f, 0.f, 0.f, 0.f};

  const int lrow = lane >> 2;
  const int lk = (lane & 3) << 3;
  const int fr = lane & 15, fk = (lane >> 4) << 3;

  for (int k0 = 0; k0 < K; k0 += 32) {
#pragma unroll
    for (int r = 0; r < 2; ++r) {
      int rowA = r * 64 + wave * 16;  // wave-uniform
      size_t goffA = (size_t)(tm + rowA + lrow) * K + k0 + lk;
      size_t goffB = (size_t)(tn + rowA + lrow) * K + k0 + lk;
      __builtin_amdgcn_global_load_lds((const __attribute__((address_space(1))) void*)(A + goffA),
                                       (__attribute__((address_space(3))) void*)&lsA[rowA * 32],
                                       16, 0, 0);
      __builtin_amdgcn_global_load_lds((const __attribute__((address_space(1))) void*)(Bm + goffB),
                                       (__attribute__((address_space(3))) void*)&lsB[rowA * 32],
                                       16, 0, 0);
      if constexpr (TERMS == 3) {
        __builtin_amdgcn_global_load_lds((const __attribute__((address_space(1))) void*)(Al + goffA),
                                         (__attribute__((address_space(3))) void*)&lsAl[rowA * 32],
                                         16, 0, 0);
        __builtin_amdgcn_global_load_lds((const __attribute__((address_space(1))) void*)(Bl + goffB),
                                         (__attribute__((address_space(3))) void*)&lsBl[rowA * 32],
                                         16, 0, 0);
      }
    }
    __syncthreads();
    s16x8 av[4], bv[4];
#pragma unroll
    for (int mi = 0; mi < 4; ++mi)
      av[mi] = *reinterpret_cast<const s16x8*>(&lsA[(wr * 64 + mi * 16 + fr) * 32 + fk]);
#pragma unroll
    for (int ni = 0; ni < 4; ++ni)
      bv[ni] = *reinterpret_cast<const s16x8*>(&lsB[(wc * 64 + ni * 16 + fr) * 32 + fk]);
    if constexpr (TERMS == 3) {
      s16x8 avl[4], bvl[4];
#pragma unroll
      for (int mi = 0; mi < 4; ++mi)
        avl[mi] = *reinterpret_cast<const s16x8*>(&lsAl[(wr * 64 + mi * 16 + fr) * 32 + fk]);
#pragma unroll
      for (int ni = 0; ni < 4; ++ni)
        bvl[ni] = *reinterpret_cast<const s16x8*>(&lsBl[(wc * 64 + ni * 16 + fr) * 32 + fk]);
#pragma unroll
      for (int mi = 0; mi < 4; ++mi)
#pragma unroll
        for (int ni = 0; ni < 4; ++ni) {
          acc[mi][ni] = __builtin_amdgcn_mfma_f32_16x16x32_bf16(av[mi], bv[ni], acc[mi][ni], 0, 0, 0);
          acc[mi][ni] = __builtin_amdgcn_mfma_f32_16x16x32_bf16(av[mi], bvl[ni], acc[mi][ni], 0, 0, 0);
          acc[mi][ni] = __builtin_amdgcn_mfma_f32_16x16x32_bf16(avl[mi], bv[ni], acc[mi][ni], 0, 0, 0);
        }
    } else {
#pragma unroll
      for (int mi = 0; mi < 4; ++mi)
#pragma unroll
        for (int ni = 0; ni < 4; ++ni)
          acc[mi][ni] = __builtin_amdgcn_mfma_f32_16x16x32_bf16(av[mi], bv[ni], acc[mi][ni], 0, 0, 0);
    }
    __syncthreads();
  }

  const int fm = (lane >> 4) << 2;
#pragma unroll
  for (int ni = 0; ni < 4; ++ni) {
    int col = tn + wc * 64 + ni * 16 + fr;
    float badd = 0.f;
    if constexpr (BIAS) badd = bias[col];
#pragma unroll
    for (int mi = 0; mi < 4; ++mi) {
#pragma unroll
      for (int r = 0; r < 4; ++r) {
        int row = tm + wr * 64 + mi * 16 + fm + r;
        size_t idx = (size_t)row * N + col;
        float v = acc[mi][ni][r] + badd;
        if constexpr (OUTBF) Cb[idx] = f2bf(v);
        else Cf[idx] = v;
      }
    }
  }
}

template <bool BIAS, bool OUTBF, int TERMS>
__global__ __launch_bounds__(256) void k_gemm(const u16* __restrict__ A,
                                              const u16* __restrict__ Al,
                                              const u16* __restrict__ Bm,
                                              const u16* __restrict__ Bl,
                                              float* __restrict__ Cf, u16* __restrict__ Cb,
                                              const float* __restrict__ bias,
                                              int M, int N, int K) {
  __shared__ u16 ls[4 * 128 * 32];
  gemm_body<BIAS, OUTBF, TERMS>(ls, blockIdx.x, threadIdx.x, A, Al, Bm, Bl, Cf, Cb, bias, M, N, K);
}

// ---------------- logits: tiled k_gemm with XCD-aware tile swizzle ----------------
// 2000 tiles (8 M x 250 N). Swizzle so all 8 M-tiles of panel n share id%8 (same XCD)
// and are consecutive there: B panel read once into that XCD's L2.
__global__ __launch_bounds__(256) void k_logits_sw(const u16* __restrict__ hmid,
                                                   const u16* __restrict__ Vp_bf,
                                                   const float* __restrict__ Vp_b,
                                                   float* __restrict__ outp) {
  __shared__ u16 ls[4 * 128 * 32];
  const int id = blockIdx.x;
  const int n = (id & 7) + 8 * (id >> 6);
  const int m = (id >> 3) & 7;
  if (n >= 250) return;
  gemm_body<true, false, 1>(ls, n * 8 + m, threadIdx.x, hmid, nullptr, Vp_bf, nullptr,
                            outp, nullptr, Vp_b, 1024, 32000, 512);
}

// ---------------- persistent LSTM body — EXACT R3/R5 protocol (proven 343us) --------
// DO NOT MODIFY: R4 (XCD-local) hung; R6 (sentinel) +200us; R9 (atomic h loads) +200us.
DEV void lstm_body(int w, int tid, float* gls,
                   const float* __restrict__ xg, const float* __restrict__ Whh,
                   const float* __restrict__ cell, unsigned* __restrict__ hpack,
                   u16* __restrict__ out_hi, u16* __restrict__ out_lo,
                   int* __restrict__ flags) {
  const int gi = tid >> 6, lane = tid & 63;
  const int ds0 = w << 4;
  float (*g_lds)[16][16] = (float(*)[16][16])gls;

  const int fr = lane & 15;          // A-frag row (batch)
  const int fkb = (lane >> 4) << 3;  // k element base

  s16x8 whi[16], wlo[16];
  {
    const float* wrow = Whh + (size_t)(gi * Dd + ds0 + fr) * Dd;
#pragma unroll
    for (int kc = 0; kc < 16; ++kc) {
      int k = kc * 32 + fkb;
      float4 a = *reinterpret_cast<const float4*>(&wrow[k]);
      float4 b = *reinterpret_cast<const float4*>(&wrow[k + 4]);
      float vv[8] = {a.x, a.y, a.z, a.w, b.x, b.y, b.z, b.w};
#pragma unroll
      for (int j = 0; j < 8; ++j) {
        u16 h = f2bf(vv[j]);
        whi[kc][j] = (short)h;
        wlo[kc][j] = (short)f2bf(vv[j] - bf2f(h));
      }
    }
  }

  const int ub = tid >> 4, ud = tid & 15;  // update mapping: batch, d-offset
  float c = cell[(size_t)ub * Dd + ds0 + ud];

  for (int t = 0; t < Tt; ++t) {
    float xgv[4];
#pragma unroll
    for (int r = 0; r < 4; ++r) {
      int bb = ((lane >> 4) << 2) + r;
      xgv[r] = xg[(size_t)(bb * Tt + t) * FD + gi * Dd + ds0 + fr];
    }
#pragma unroll
    for (int r = 0; r < 4; ++r) asm volatile("" ::"v"(xgv[r]));  // pin issue before poll

    if (t > 0) {
      if (gi == 0) {
        if (lane < 32 && lane != w) {
          while (__hip_atomic_load(&flags[lane * 32], __ATOMIC_RELAXED,
                                   __HIP_MEMORY_SCOPE_AGENT) < t) {}
          while (__hip_atomic_load(&flags[lane * 32], __ATOMIC_ACQUIRE,
                                   __HIP_MEMORY_SCOPE_AGENT) < t) {}
        }
        __builtin_amdgcn_sched_barrier(0);
      }
      __syncthreads();  // other waves' hpack loads ordered after wave0's invalidate
    }

    const unsigned* hp = hpack + (size_t)t * (Bb * Dd) + (size_t)fr * Dd;
    f32x4 a0 = (f32x4){0.f, 0.f, 0.f, 0.f};
    f32x4 a1 = a0, a2 = a0;
#pragma unroll
    for (int kc = 0; kc < 16; ++kc) {
      int k = kc * 32 + fkb;
      u32x4 u0 = *reinterpret_cast<const u32x4*>(&hp[k]);
      u32x4 u1 = *reinterpret_cast<const u32x4*>(&hp[k + 4]);
      s16x8 ahi, alo;
#pragma unroll
      for (int j = 0; j < 4; ++j) {
        ahi[j] = (short)(u0[j] & 0xffffu); alo[j] = (short)(u0[j] >> 16);
        ahi[4 + j] = (short)(u1[j] & 0xffffu); alo[4 + j] = (short)(u1[j] >> 16);
      }
      a0 = __builtin_amdgcn_mfma_f32_16x16x32_bf16(ahi, whi[kc], a0, 0, 0, 0);
      a1 = __builtin_amdgcn_mfma_f32_16x16x32_bf16(ahi, wlo[kc], a1, 0, 0, 0);
      a2 = __builtin_amdgcn_mfma_f32_16x16x32_bf16(alo, whi[kc], a2, 0, 0, 0);
    }
#pragma unroll
    for (int r = 0; r < 4; ++r) {
      int bb = ((lane >> 4) << 2) + r;
      g_lds[gi][bb][fr] = a0[r] + a1[r] + a2[r] + xgv[r];
    }
    __syncthreads();
    float iv = g_lds[0][ub][ud], fv = g_lds[1][ub][ud];
    float gv = g_lds[2][ub][ud], ov = g_lds[3][ub][ud];
    c = sigm(fv) * c + sigm(iv) * ftanh(gv);
    float h = sigm(ov) * ftanh(c);
    u16 hh = f2bf(h);
    u16 hl = f2bf(h - bf2f(hh));
    unsigned pk = (unsigned)hh | ((unsigned)hl << 16);
    __hip_atomic_store(&hpack[(size_t)(t + 1) * (Bb * Dd) + ub * Dd + ds0 + ud], pk,
                       __ATOMIC_RELAXED, __HIP_MEMORY_SCOPE_AGENT);
    size_t oidx = (size_t)(ub * Tt + t) * Dd + ds0 + ud;
    out_hi[oidx] = hh;
    out_lo[oidx] = hl;
    __syncthreads();  // drains vmcnt in every wave: h stores complete at LLC
    if (tid == 0)
      __hip_atomic_store(&flags[w * 32], t + 1, __ATOMIC_RELAXED, __HIP_MEMORY_SCOPE_AGENT);
  }
}

// ---------------- fused: LSTM (blocks 0-31) + independent side work ----------------
__global__ __launch_bounds__(256) void k_lstm_fused(
    const float* __restrict__ xg, const float* __restrict__ Whh,
    const float* __restrict__ cell, unsigned* __restrict__ hpack,
    u16* __restrict__ out_hi, u16* __restrict__ out_lo, int* __restrict__ flags,
    const u16* __restrict__ enc_hi, const u16* __restrict__ enc_lo,
    const u16* __restrict__ Whw_hi, const u16* __restrict__ Whw_lo,
    float* __restrict__ wh,
    const float* __restrict__ Vp_w, u16* __restrict__ Vp_bf,
    const float* __restrict__ V_w, u16* __restrict__ Vw_bf,
    const float* __restrict__ Ws_w, u16* __restrict__ Wsw_hi, u16* __restrict__ Wsw_lo) {
  __shared__ u16 ls[4 * 128 * 32];
  const int blk = blockIdx.x, tid = threadIdx.x;
  if (blk < 32) {
    lstm_body(blk, tid, (float*)ls, xg, Whh, cell, hpack, out_hi, out_lo, flags);
  } else if (blk < 96) {
    gemm_body<false, false, 3>(ls, blk - 32, tid, enc_hi, enc_lo, Whw_hi, Whw_lo,
                               wh, nullptr, nullptr, 2048, 512, 512);
  } else {
    const int nVp = Vv * Dd / 4, nV = Dd * 2 * Dd / 4, nWs = Dd * Dd / 4;
    int total = nVp + nV + nWs;
    int i = (blk - 96) * 256 + tid;
    int st = 160 * 256;
    for (; i < total; i += st) {
      if (i < nVp) cvt_plain_one(Vp_w, Vp_bf, i);
      else if (i < nVp + nV) cvt_plain_one(V_w, Vw_bf, i - nVp);
      else cvt_split_one(Ws_w, Wsw_hi, Wsw_lo, i - nVp - nV);
    }
  }
}

// ---------------- fused tail: ws -> attention -> V, row-local per block ----------
// 128 blocks; block (b, tc) owns the 8 rows t = tc*8 + j. The whole ws->attn->V
// chain is per-row local (R8 proved the fusion's numerics; R8's failure was running
// it DURING the LSTM — standalone, each XCD's L2 caches the 3MB Wsw+Vw once).
// Replaces 3 kernels + the wst/cat global round-trips.
__global__ __launch_bounds__(256) void k_tail(
    const u16* __restrict__ out_hi, const u16* __restrict__ out_lo,
    const u16* __restrict__ Wsw_hi, const u16* __restrict__ Wsw_lo,
    const float* __restrict__ Ws_b,
    const float* __restrict__ wh, const float* __restrict__ vt,
    const float* __restrict__ enc,
    const u16* __restrict__ Vw_bf, const float* __restrict__ V_b,
    u16* __restrict__ hmid) {
  __shared__ float ws_s[8][Dd];        // 16 KB
  __shared__ u16 cat_s[8][2 * Dd];     // 16 KB
  const int blk = blockIdx.x, tid = threadIdx.x;
  const int b = blk >> 3, tc = blk & 7;  // rows b*Tt + tc*8 + j, j in [0,8)
  const int wv = tid >> 6, lane = tid & 63;
  const int fr = lane & 15, fkb = (lane >> 4) << 3;

  // ---- ws = out @ Wsw^T + Ws_b (3-term split); wave wv owns cols [wv*128, +128) ----
  {
    f32x4 acc8[8];
#pragma unroll
    for (int n = 0; n < 8; ++n) acc8[n] = (f32x4){0.f, 0.f, 0.f, 0.f};
    const int j = fr & 7;  // A-frag rows 8..15 duplicate 0..7; discarded at write
    const size_t arow = (size_t)(b * Tt + tc * 8 + j) * Dd;
    for (int kc = 0; kc < 16; ++kc) {
      int k = kc * 32 + fkb;
      s16x8 ah = *reinterpret_cast<const s16x8*>(&out_hi[arow + k]);
      s16x8 al = *reinterpret_cast<const s16x8*>(&out_lo[arow + k]);
#pragma unroll
      for (int n = 0; n < 8; ++n) {
        size_t brow = (size_t)(wv * 128 + n * 16 + fr) * Dd + k;
        s16x8 bh = *reinterpret_cast<const s16x8*>(&Wsw_hi[brow]);
        s16x8 bl = *reinterpret_cast<const s16x8*>(&Wsw_lo[brow]);
        acc8[n] = __builtin_amdgcn_mfma_f32_16x16x32_bf16(ah, bh, acc8[n], 0, 0, 0);
        acc8[n] = __builtin_amdgcn_mfma_f32_16x16x32_bf16(ah, bl, acc8[n], 0, 0, 0);
        acc8[n] = __builtin_amdgcn_mfma_f32_16x16x32_bf16(al, bh, acc8[n], 0, 0, 0);
      }
    }
#pragma unroll
    for (int n = 0; n < 8; ++n) {
      int col = wv * 128 + n * 16 + fr;
      float badd = Ws_b[col];
#pragma unroll
      for (int r = 0; r < 4; ++r) {
        int row = (lane >> 4) * 4 + r;
        if (row < 8) ws_s[row][col] = acc8[n][r] + badd;
      }
    }
  }
  __syncthreads();

  // ---- attention: wave wv handles rows j = wv*2, wv*2+1 ----
  {
    const int d0 = lane << 3;
    float vtv[8];
    {
      const float4* q = reinterpret_cast<const float4*>(&vt[d0]);
      float4 u = q[0], v = q[1];
      vtv[0] = u.x; vtv[1] = u.y; vtv[2] = u.z; vtv[3] = u.w;
      vtv[4] = v.x; vtv[5] = v.y; vtv[6] = v.z; vtv[7] = v.w;
    }
    for (int rr = 0; rr < 2; ++rr) {
      int j = wv * 2 + rr;
      float wsv[8];
#pragma unroll
      for (int d = 0; d < 8; ++d) wsv[d] = ws_s[j][d0 + d];
      float e0 = 0.f, e1 = 0.f;
      for (int s = 0; s < Ss; ++s) {
        const float4* p = reinterpret_cast<const float4*>(&wh[(size_t)(b * Ss + s) * Dd + d0]);
        float4 x = p[0], y = p[1];
        float whv[8] = {x.x, x.y, x.z, x.w, y.x, y.y, y.z, y.w};
        float a = 0.f;
#pragma unroll
        for (int d = 0; d < 8; ++d) a += ftanh(whv[d] + wsv[d]) * vtv[d];
#pragma unroll
        for (int off = 32; off; off >>= 1) a += __shfl_xor(a, off);
        if (lane == (s & 63)) { if (s < 64) e0 = a; else e1 = a; }
      }
      float m = fmaxf(e0, e1);
#pragma unroll
      for (int off = 32; off; off >>= 1) m = fmaxf(m, __shfl_xor(m, off));
      float p0 = __expf(e0 - m), p1 = __expf(e1 - m);
      float sum = p0 + p1;
#pragma unroll
      for (int off = 32; off; off >>= 1) sum += __shfl_xor(sum, off);
      float inv = 1.f / sum;
      float a0s = p0 * inv, a1s = p1 * inv;
      float ctx[8] = {0.f, 0.f, 0.f, 0.f, 0.f, 0.f, 0.f, 0.f};
      for (int s = 0; s < Ss; ++s) {
        float as = __shfl(s < 64 ? a0s : a1s, s & 63);
        const float4* p = reinterpret_cast<const float4*>(&enc[(size_t)(b * Ss + s) * Dd + d0]);
        float4 x = p[0], y = p[1];
        ctx[0] += as * x.x; ctx[1] += as * x.y; ctx[2] += as * x.z; ctx[3] += as * x.w;
        ctx[4] += as * y.x; ctx[5] += as * y.y; ctx[6] += as * y.z; ctx[7] += as * y.w;
      }
      u16x8 co;
#pragma unroll
      for (int d = 0; d < 8; ++d) co[d] = f2bf(ctx[d]);
      *reinterpret_cast<u16x8*>(&cat_s[j][d0]) = co;
      size_t orow = (size_t)(b * Tt + tc * 8 + j) * Dd;
      u16x8 ov = *reinterpret_cast<const u16x8*>(&out_hi[orow + d0]);
      *reinterpret_cast<u16x8*>(&cat_s[j][Dd + d0]) = ov;
    }
  }
  __syncthreads();

  // ---- hmid = cat @ V^T + V_b -> bf16 ----
  {
    f32x4 acc8[8];
#pragma unroll
    for (int n = 0; n < 8; ++n) acc8[n] = (f32x4){0.f, 0.f, 0.f, 0.f};
    const int j = fr & 7;
    for (int kc = 0; kc < 32; ++kc) {
      int k = kc * 32 + fkb;
      s16x8 a = *reinterpret_cast<const s16x8*>(&cat_s[j][k]);
#pragma unroll
      for (int n = 0; n < 8; ++n) {
        size_t brow = (size_t)(wv * 128 + n * 16 + fr) * (2 * Dd) + k;
        s16x8 bf = *reinterpret_cast<const s16x8*>(&Vw_bf[brow]);
        acc8[n] = __builtin_amdgcn_mfma_f32_16x16x32_bf16(a, bf, acc8[n], 0, 0, 0);
      }
    }
#pragma unroll
    for (int n = 0; n < 8; ++n) {
      int col = wv * 128 + n * 16 + fr;
      float badd = V_b[col];
#pragma unroll
      for (int r = 0; r < 4; ++r) {
        int row = (lane >> 4) * 4 + r;
        if (row < 8)
          hmid[(size_t)(b * Tt + tc * 8 + row) * Dd + col] = f2bf(acc8[n][r] + badd);
      }
    }
  }
}

// ---------------- host ----------------
extern "C" void kernel_launch(void* const* d_in, const int* in_sizes, int n_in,
                              void* d_out, int out_size, void* d_ws, size_t ws_size,
                              hipStream_t stream) {
  const int* words = (const int*)d_in[0];
  const float* enc = (const float*)d_in[1];
  const float* pre_h = (const float*)d_in[2];
  const float* cell = (const float*)d_in[3];
  const float* emb = (const float*)d_in[4];
  const float* W_ih = (const float*)d_in[5];
  const float* W_hh = (const float*)d_in[6];
  const float* b_ih = (const float*)d_in[7];
  const float* b_hh = (const float*)d_in[8];
  const float* Wh_w = (const float*)d_in[9];
  const float* Ws_w = (const float*)d_in[10];
  const float* Ws_b = (const float*)d_in[11];
  const float* vt_w = (const float*)d_in[12];
  const float* V_w = (const float*)d_in[13];
  const float* V_b = (const float*)d_in[14];
  const float* Vp_w = (const float*)d_in[15];
  const float* Vp_b = (const float*)d_in[16];
  float* outp = (float*)d_out;

  char* ws = (char*)d_ws;
  size_t off = 0;
  auto alloc = [&](size_t bytes) {
    char* p = ws + off;
    off = (off + bytes + 255) & ~(size_t)255;
    return p;
  };
  int* flags = (int*)alloc(4096);                             // 32 x 128B lines
  float* xg = (float*)alloc((size_t)Bb * Tt * FD * 4);        // 8 MB
  float* wh = (float*)alloc((size_t)Bb * Ss * Dd * 4);        // 4 MB
  unsigned* hpack = (unsigned*)alloc((size_t)(Tt + 1) * Bb * Dd * 4);
  u16* out_hi = (u16*)alloc((size_t)Bb * Tt * Dd * 2);
  u16* out_lo = (u16*)alloc((size_t)Bb * Tt * Dd * 2);
  u16* x_bf = (u16*)alloc((size_t)Bb * Tt * Dd * 2);
  u16* enc_hi = (u16*)alloc((size_t)Bb * Ss * Dd * 2);
  u16* enc_lo = (u16*)alloc((size_t)Bb * Ss * Dd * 2);
  u16* Wih_bf = (u16*)alloc((size_t)FD * Dd * 2);
  u16* Whw_hi = (u16*)alloc((size_t)Dd * Dd * 2);
  u16* Whw_lo = (u16*)alloc((size_t)Dd * Dd * 2);
  u16* Wsw_hi = (u16*)alloc((size_t)Dd * Dd * 2);
  u16* Wsw_lo = (u16*)alloc((size_t)Dd * Dd * 2);
  u16* Vw_bf = (u16*)alloc((size_t)Dd * 2 * Dd * 2);
  u16* Vp_bf = (u16*)alloc((size_t)Vv * Dd * 2);              // 32.8 MB
  u16* hmid = (u16*)alloc((size_t)Bb * Tt * Dd * 2);
  float* bsum = (float*)alloc((size_t)FD * 4);
  if (off > ws_size) return;  // workspace too small: fail cleanly

  hipMemsetAsync(flags, 0, 4096, stream);

  // fused prologue: embed + preh + bsum + (Wih, enc, Whw) converts
  k_pre<<<Bb * Tt + 40 + 256, 256, 0, stream>>>(words, emb, x_bf, pre_h, (unsigned*)hpack,
                                                b_ih, b_hh, bsum,
                                                W_ih, Wih_bf, enc, enc_hi, enc_lo,
                                                Wh_w, Whw_hi, Whw_lo);
  // xg = x @ W_ih^T + (b_ih + b_hh)   [1024, 2048]
  k_gemm<true, false, 1><<<8 * 16, 256, 0, stream>>>(x_bf, nullptr, Wih_bf, nullptr,
                                                     xg, nullptr, bsum, 1024, 2048, 512);
  // LSTM (blocks 0-31, R5 protocol) + side work: wh GEMM + Vp/V/Ws converts
  k_lstm_fused<<<256, 256, 0, stream>>>(xg, W_hh, cell, (unsigned*)hpack, out_hi, out_lo,
                                        flags, enc_hi, enc_lo, Whw_hi, Whw_lo, wh,
                                        Vp_w, Vp_bf, V_w, Vw_bf, Ws_w, Wsw_hi, Wsw_lo);
  // fused tail: ws -> attention -> V (row-local), replaces 3 kernels
  k_tail<<<128, 256, 0, stream>>>(out_hi, out_lo, Wsw_hi, Wsw_lo, Ws_b,
                                  wh, vt_w, enc, Vw_bf, V_b, hmid);
  // logits = hmid @ Vp_w^T + Vp_b  [1024, 32000] — XCD-swizzled tiled GEMM
  k_logits_sw<<<2048, 256, 0, stream>>>(hmid, Vp_bf, Vp_b, outp);
}

// Round 13
// 580.701 us; speedup vs baseline: 1.2362x; 1.2362x over previous
//
#include <hip/hip_runtime.h>

#define DEV __device__ __forceinline__

typedef float f32x4 __attribute__((ext_vector_type(4)));
typedef short s16x8 __attribute__((ext_vector_type(8)));
typedef unsigned short u16;
typedef u16 u16x4 __attribute__((ext_vector_type(4)));
typedef u16 u16x8 __attribute__((ext_vector_type(8)));
typedef unsigned int u32x4 __attribute__((ext_vector_type(4)));

constexpr int Bb = 16, Tt = 64, Ss = 128, Dd = 512, Vv = 32000, FD = 2048;

DEV u16 f2bf(float x) {                       // RNE f32 -> bf16
  unsigned u = __builtin_bit_cast(unsigned, x);
  u = u + 0x7fffu + ((u >> 16) & 1u);
  return (u16)(u >> 16);
}
DEV float bf2f(u16 h) { unsigned u = ((unsigned)h) << 16; return __builtin_bit_cast(float, u); }
DEV float sigm(float x) { return 1.f / (1.f + __expf(-x)); }
DEV float ftanh(float x) {
  x = fminf(15.f, fmaxf(-15.f, x));
  float e = __expf(2.f * x);
  return (e - 1.f) / (e + 1.f);
}

DEV void cvt_plain_one(const float* __restrict__ in, u16* __restrict__ out, int i) {
  float4 v = reinterpret_cast<const float4*>(in)[i];
  u16x4 o;
  o.x = f2bf(v.x); o.y = f2bf(v.y); o.z = f2bf(v.z); o.w = f2bf(v.w);
  reinterpret_cast<u16x4*>(out)[i] = o;
}

DEV void cvt_split_one(const float* __restrict__ in, u16* __restrict__ hi,
                       u16* __restrict__ lo, int i) {
  float4 v = reinterpret_cast<const float4*>(in)[i];
  u16x4 oh, ol;
  float vv[4] = {v.x, v.y, v.z, v.w};
#pragma unroll
  for (int j = 0; j < 4; ++j) {
    u16 h = f2bf(vv[j]);
    oh[j] = h;
    ol[j] = f2bf(vv[j] - bf2f(h));
  }
  reinterpret_cast<u16x4*>(hi)[i] = oh;
  reinterpret_cast<u16x4*>(lo)[i] = ol;
}

// ---------------- fused prologue: embed + preh + bsum + (Wih, enc, Whw) converts -----
__global__ void k_pre(const int* __restrict__ words, const float* __restrict__ emb,
                      u16* __restrict__ xb,
                      const float* __restrict__ pre, unsigned* __restrict__ hp0,
                      const float* __restrict__ bi, const float* __restrict__ bh,
                      float* __restrict__ bsum,
                      const float* __restrict__ Wih, u16* __restrict__ Wih_bf,
                      const float* __restrict__ enc, u16* __restrict__ ench,
                      u16* __restrict__ encl,
                      const float* __restrict__ Whw, u16* __restrict__ whh,
                      u16* __restrict__ whl) {
  int blk = blockIdx.x, tid = threadIdx.x;
  if (blk < Bb * Tt) {
    int row = words[blk];
    int d = tid * 2;
    float2 v = *reinterpret_cast<const float2*>(&emb[(size_t)row * Dd + d]);
    xb[(size_t)blk * Dd + d] = f2bf(v.x);
    xb[(size_t)blk * Dd + d + 1] = f2bf(v.y);
  } else if (blk < Bb * Tt + 32) {
    int i = (blk - Bb * Tt) * 256 + tid;  // Bb*Dd = 8192
    float v = pre[i];
    u16 h = f2bf(v);
    u16 l = f2bf(v - bf2f(h));
    hp0[i] = (unsigned)h | ((unsigned)l << 16);
  } else if (blk < Bb * Tt + 40) {
    int i = (blk - Bb * Tt - 32) * 256 + tid;  // FD = 2048
    bsum[i] = bi[i] + bh[i];
  } else {
    const int n0 = FD * Dd / 4, n1 = Bb * Ss * Dd / 4, n2 = Dd * Dd / 4;
    int total = n0 + n1 + n2;
    int i = (blk - (Bb * Tt + 40)) * 256 + tid;
    int st = 256 * 256;
    for (; i < total; i += st) {
      if (i < n0) cvt_plain_one(Wih, Wih_bf, i);
      else if (i < n0 + n1) cvt_split_one(enc, ench, encl, i - n0);
      else cvt_split_one(Whw, whh, whl, i - n0 - n1);
    }
  }
}

// ---------------- bf16 GEMM body: C[M,N] = A[M,K] @ B[N,K]^T (+bias) ----------------
// 128x128 tile, BK=32, 4 waves each owning a 64x64 quadrant (4x4 frags of 16x16x32 MFMA).
// TERMS==3: split-bf16 A=(Ah+Al), B=(Bh+Bl); computes Ah*Bh + Ah*Bl + Al*Bh fused.
template <bool BIAS, bool OUTBF, int TERMS>
DEV void gemm_body(u16* ls, int tile, int tid,
                   const u16* __restrict__ A, const u16* __restrict__ Al,
                   const u16* __restrict__ Bm, const u16* __restrict__ Bl,
                   float* __restrict__ Cf, u16* __restrict__ Cb,
                   const float* __restrict__ bias, int M, int N, int K) {
  u16* lsA = ls;
  u16* lsB = ls + 128 * 32;
  u16* lsAl = ls + 2 * 128 * 32;
  u16* lsBl = ls + 3 * 128 * 32;
  const int mt = M >> 7;
  const int tm = (tile % mt) << 7;
  const int tn = (tile / mt) << 7;
  const int wave = tid >> 6, lane = tid & 63;
  const int wr = wave >> 1, wc = wave & 1;
  f32x4 acc[4][4];
#pragma unroll
  for (int i = 0; i < 4; ++i)
#pragma unroll
    for (int j = 0; j < 4; ++j) acc[i][j] = (f32x4){0.f, 0.f, 0.f, 0.f};

  const int lrow = lane >> 2;
  const int lk = (lane & 3) << 3;
  const int fr = lane & 15, fk = (lane >> 4) << 3;

  for (int k0 = 0; k0 < K; k0 += 32) {
#pragma unroll
    for (int r = 0; r < 2; ++r) {
      int rowA = r * 64 + wave * 16;  // wave-uniform
      size_t goffA = (size_t)(tm + rowA + lrow) * K + k0 + lk;
      size_t goffB = (size_t)(tn + rowA + lrow) * K + k0 + lk;
      __builtin_amdgcn_global_load_lds((const __attribute__((address_space(1))) void*)(A + goffA),
                                       (__attribute__((address_space(3))) void*)&lsA[rowA * 32],
                                       16, 0, 0);
      __builtin_amdgcn_global_load_lds((const __attribute__((address_space(1))) void*)(Bm + goffB),
                                       (__attribute__((address_space(3))) void*)&lsB[rowA * 32],
                                       16, 0, 0);
      if constexpr (TERMS == 3) {
        __builtin_amdgcn_global_load_lds((const __attribute__((address_space(1))) void*)(Al + goffA),
                                         (__attribute__((address_space(3))) void*)&lsAl[rowA * 32],
                                         16, 0, 0);
        __builtin_amdgcn_global_load_lds((const __attribute__((address_space(1))) void*)(Bl + goffB),
                                         (__attribute__((address_space(3))) void*)&lsBl[rowA * 32],
                                         16, 0, 0);
      }
    }
    __syncthreads();
    s16x8 av[4], bv[4];
#pragma unroll
    for (int mi = 0; mi < 4; ++mi)
      av[mi] = *reinterpret_cast<const s16x8*>(&lsA[(wr * 64 + mi * 16 + fr) * 32 + fk]);
#pragma unroll
    for (int ni = 0; ni < 4; ++ni)
      bv[ni] = *reinterpret_cast<const s16x8*>(&lsB[(wc * 64 + ni * 16 + fr) * 32 + fk]);
    if constexpr (TERMS == 3) {
      s16x8 avl[4], bvl[4];
#pragma unroll
      for (int mi = 0; mi < 4; ++mi)
        avl[mi] = *reinterpret_cast<const s16x8*>(&lsAl[(wr * 64 + mi * 16 + fr) * 32 + fk]);
#pragma unroll
      for (int ni = 0; ni < 4; ++ni)
        bvl[ni] = *reinterpret_cast<const s16x8*>(&lsBl[(wc * 64 + ni * 16 + fr) * 32 + fk]);
#pragma unroll
      for (int mi = 0; mi < 4; ++mi)
#pragma unroll
        for (int ni = 0; ni < 4; ++ni) {
          acc[mi][ni] = __builtin_amdgcn_mfma_f32_16x16x32_bf16(av[mi], bv[ni], acc[mi][ni], 0, 0, 0);
          acc[mi][ni] = __builtin_amdgcn_mfma_f32_16x16x32_bf16(av[mi], bvl[ni], acc[mi][ni], 0, 0, 0);
          acc[mi][ni] = __builtin_amdgcn_mfma_f32_16x16x32_bf16(avl[mi], bv[ni], acc[mi][ni], 0, 0, 0);
        }
    } else {
#pragma unroll
      for (int mi = 0; mi < 4; ++mi)
#pragma unroll
        for (int ni = 0; ni < 4; ++ni)
          acc[mi][ni] = __builtin_amdgcn_mfma_f32_16x16x32_bf16(av[mi], bv[ni], acc[mi][ni], 0, 0, 0);
    }
    __syncthreads();
  }

  const int fm = (lane >> 4) << 2;
#pragma unroll
  for (int ni = 0; ni < 4; ++ni) {
    int col = tn + wc * 64 + ni * 16 + fr;
    float badd = 0.f;
    if constexpr (BIAS) badd = bias[col];
#pragma unroll
    for (int mi = 0; mi < 4; ++mi) {
#pragma unroll
      for (int r = 0; r < 4; ++r) {
        int row = tm + wr * 64 + mi * 16 + fm + r;
        size_t idx = (size_t)row * N + col;
        float v = acc[mi][ni][r] + badd;
        if constexpr (OUTBF) Cb[idx] = f2bf(v);
        else Cf[idx] = v;
      }
    }
  }
}

template <bool BIAS, bool OUTBF, int TERMS>
__global__ __launch_bounds__(256) void k_gemm(const u16* __restrict__ A,
                                              const u16* __restrict__ Al,
                                              const u16* __restrict__ Bm,
                                              const u16* __restrict__ Bl,
                                              float* __restrict__ Cf, u16* __restrict__ Cb,
                                              const float* __restrict__ bias,
                                              int M, int N, int K) {
  __shared__ u16 ls[4 * 128 * 32];
  gemm_body<BIAS, OUTBF, TERMS>(ls, blockIdx.x, threadIdx.x, A, Al, Bm, Bl, Cf, Cb, bias, M, N, K);
}

// ---------------- logits: tiled k_gemm with XCD-aware tile swizzle ----------------
// 2000 tiles (8 M x 250 N). Swizzle so all 8 M-tiles of panel n share id%8 (same XCD)
// and are consecutive there: B panel read once into that XCD's L2.
__global__ __launch_bounds__(256) void k_logits_sw(const u16* __restrict__ hmid,
                                                   const u16* __restrict__ Vp_bf,
                                                   const float* __restrict__ Vp_b,
                                                   float* __restrict__ outp) {
  __shared__ u16 ls[4 * 128 * 32];
  const int id = blockIdx.x;
  const int n = (id & 7) + 8 * (id >> 6);
  const int m = (id >> 3) & 7;
  if (n >= 250) return;
  gemm_body<true, false, 1>(ls, n * 8 + m, threadIdx.x, hmid, nullptr, Vp_bf, nullptr,
                            outp, nullptr, Vp_b, 1024, 32000, 512);
}

// ---------------- persistent LSTM body — EXACT R3/R5 protocol (proven 343us) --------
// DO NOT MODIFY: R4 (XCD-local) hung; R6 (sentinel) +200us; R9 (atomic h loads) +200us.
DEV void lstm_body(int w, int tid, float* gls,
                   const float* __restrict__ xg, const float* __restrict__ Whh,
                   const float* __restrict__ cell, unsigned* __restrict__ hpack,
                   u16* __restrict__ out_hi, u16* __restrict__ out_lo,
                   int* __restrict__ flags) {
  const int gi = tid >> 6, lane = tid & 63;
  const int ds0 = w << 4;
  float (*g_lds)[16][16] = (float(*)[16][16])gls;

  const int fr = lane & 15;          // A-frag row (batch)
  const int fkb = (lane >> 4) << 3;  // k element base

  s16x8 whi[16], wlo[16];
  {
    const float* wrow = Whh + (size_t)(gi * Dd + ds0 + fr) * Dd;
#pragma unroll
    for (int kc = 0; kc < 16; ++kc) {
      int k = kc * 32 + fkb;
      float4 a = *reinterpret_cast<const float4*>(&wrow[k]);
      float4 b = *reinterpret_cast<const float4*>(&wrow[k + 4]);
      float vv[8] = {a.x, a.y, a.z, a.w, b.x, b.y, b.z, b.w};
#pragma unroll
      for (int j = 0; j < 8; ++j) {
        u16 h = f2bf(vv[j]);
        whi[kc][j] = (short)h;
        wlo[kc][j] = (short)f2bf(vv[j] - bf2f(h));
      }
    }
  }

  const int ub = tid >> 4, ud = tid & 15;  // update mapping: batch, d-offset
  float c = cell[(size_t)ub * Dd + ds0 + ud];

  for (int t = 0; t < Tt; ++t) {
    float xgv[4];
#pragma unroll
    for (int r = 0; r < 4; ++r) {
      int bb = ((lane >> 4) << 2) + r;
      xgv[r] = xg[(size_t)(bb * Tt + t) * FD + gi * Dd + ds0 + fr];
    }
#pragma unroll
    for (int r = 0; r < 4; ++r) asm volatile("" ::"v"(xgv[r]));  // pin issue before poll

    if (t > 0) {
      if (gi == 0) {
        if (lane < 32 && lane != w) {
          while (__hip_atomic_load(&flags[lane * 32], __ATOMIC_RELAXED,
                                   __HIP_MEMORY_SCOPE_AGENT) < t) {}
          while (__hip_atomic_load(&flags[lane * 32], __ATOMIC_ACQUIRE,
                                   __HIP_MEMORY_SCOPE_AGENT) < t) {}
        }
        __builtin_amdgcn_sched_barrier(0);
      }
      __syncthreads();  // other waves' hpack loads ordered after wave0's invalidate
    }

    const unsigned* hp = hpack + (size_t)t * (Bb * Dd) + (size_t)fr * Dd;
    f32x4 a0 = (f32x4){0.f, 0.f, 0.f, 0.f};
    f32x4 a1 = a0, a2 = a0;
#pragma unroll
    for (int kc = 0; kc < 16; ++kc) {
      int k = kc * 32 + fkb;
      u32x4 u0 = *reinterpret_cast<const u32x4*>(&hp[k]);
      u32x4 u1 = *reinterpret_cast<const u32x4*>(&hp[k + 4]);
      s16x8 ahi, alo;
#pragma unroll
      for (int j = 0; j < 4; ++j) {
        ahi[j] = (short)(u0[j] & 0xffffu); alo[j] = (short)(u0[j] >> 16);
        ahi[4 + j] = (short)(u1[j] & 0xffffu); alo[4 + j] = (short)(u1[j] >> 16);
      }
      a0 = __builtin_amdgcn_mfma_f32_16x16x32_bf16(ahi, whi[kc], a0, 0, 0, 0);
      a1 = __builtin_amdgcn_mfma_f32_16x16x32_bf16(ahi, wlo[kc], a1, 0, 0, 0);
      a2 = __builtin_amdgcn_mfma_f32_16x16x32_bf16(alo, whi[kc], a2, 0, 0, 0);
    }
#pragma unroll
    for (int r = 0; r < 4; ++r) {
      int bb = ((lane >> 4) << 2) + r;
      g_lds[gi][bb][fr] = a0[r] + a1[r] + a2[r] + xgv[r];
    }
    __syncthreads();
    float iv = g_lds[0][ub][ud], fv = g_lds[1][ub][ud];
    float gv = g_lds[2][ub][ud], ov = g_lds[3][ub][ud];
    c = sigm(fv) * c + sigm(iv) * ftanh(gv);
    float h = sigm(ov) * ftanh(c);
    u16 hh = f2bf(h);
    u16 hl = f2bf(h - bf2f(hh));
    unsigned pk = (unsigned)hh | ((unsigned)hl << 16);
    __hip_atomic_store(&hpack[(size_t)(t + 1) * (Bb * Dd) + ub * Dd + ds0 + ud], pk,
                       __ATOMIC_RELAXED, __HIP_MEMORY_SCOPE_AGENT);
    size_t oidx = (size_t)(ub * Tt + t) * Dd + ds0 + ud;
    out_hi[oidx] = hh;
    out_lo[oidx] = hl;
    __syncthreads();  // drains vmcnt in every wave: h stores complete at LLC
    if (tid == 0)
      __hip_atomic_store(&flags[w * 32], t + 1, __ATOMIC_RELAXED, __HIP_MEMORY_SCOPE_AGENT);
  }
}

// ---------------- fused: LSTM (blocks 0-31) + independent side work ----------------
__global__ __launch_bounds__(256) void k_lstm_fused(
    const float* __restrict__ xg, const float* __restrict__ Whh,
    const float* __restrict__ cell, unsigned* __restrict__ hpack,
    u16* __restrict__ out_hi, u16* __restrict__ out_lo, int* __restrict__ flags,
    const u16* __restrict__ enc_hi, const u16* __restrict__ enc_lo,
    const u16* __restrict__ Whw_hi, const u16* __restrict__ Whw_lo,
    float* __restrict__ wh,
    const float* __restrict__ Vp_w, u16* __restrict__ Vp_bf,
    const float* __restrict__ V_w, u16* __restrict__ Vw_bf,
    const float* __restrict__ Ws_w, u16* __restrict__ Wsw_hi, u16* __restrict__ Wsw_lo) {
  __shared__ u16 ls[4 * 128 * 32];
  const int blk = blockIdx.x, tid = threadIdx.x;
  if (blk < 32) {
    lstm_body(blk, tid, (float*)ls, xg, Whh, cell, hpack, out_hi, out_lo, flags);
  } else if (blk < 96) {
    gemm_body<false, false, 3>(ls, blk - 32, tid, enc_hi, enc_lo, Whw_hi, Whw_lo,
                               wh, nullptr, nullptr, 2048, 512, 512);
  } else {
    const int nVp = Vv * Dd / 4, nV = Dd * 2 * Dd / 4, nWs = Dd * Dd / 4;
    int total = nVp + nV + nWs;
    int i = (blk - 96) * 256 + tid;
    int st = 160 * 256;
    for (; i < total; i += st) {
      if (i < nVp) cvt_plain_one(Vp_w, Vp_bf, i);
      else if (i < nVp + nV) cvt_plain_one(V_w, Vw_bf, i - nVp);
      else cvt_split_one(Ws_w, Wsw_hi, Wsw_lo, i - nVp - nV);
    }
  }
}

// ---------------- fused attention: scores + softmax + context + concat ----------------
__global__ __launch_bounds__(256) void k_attn(const float* __restrict__ wh,
                                              const float* __restrict__ wst,
                                              const float* __restrict__ vt,
                                              const float* __restrict__ enc,
                                              const u16* __restrict__ out_hi,
                                              u16* __restrict__ cat) {
  const int tid = threadIdx.x;
  const int wave = tid >> 6, lane = tid & 63;
  const int wid = blockIdx.x * 4 + wave;
  const int b = wid >> 6, t = wid & 63;
  const int d0 = lane << 3;

  float wsv[8], vtv[8];
  {
    const float4* p = reinterpret_cast<const float4*>(&wst[(size_t)(b * Tt + t) * Dd + d0]);
    float4 x = p[0], y = p[1];
    wsv[0] = x.x; wsv[1] = x.y; wsv[2] = x.z; wsv[3] = x.w;
    wsv[4] = y.x; wsv[5] = y.y; wsv[6] = y.z; wsv[7] = y.w;
    const float4* q = reinterpret_cast<const float4*>(&vt[d0]);
    float4 u = q[0], v = q[1];
    vtv[0] = u.x; vtv[1] = u.y; vtv[2] = u.z; vtv[3] = u.w;
    vtv[4] = v.x; vtv[5] = v.y; vtv[6] = v.z; vtv[7] = v.w;
  }
  float e0 = 0.f, e1 = 0.f;
  for (int s = 0; s < Ss; ++s) {
    const float4* p = reinterpret_cast<const float4*>(&wh[(size_t)(b * Ss + s) * Dd + d0]);
    float4 x = p[0], y = p[1];
    float whv[8] = {x.x, x.y, x.z, x.w, y.x, y.y, y.z, y.w};
    float a = 0.f;
#pragma unroll
    for (int j = 0; j < 8; ++j) a += ftanh(whv[j] + wsv[j]) * vtv[j];
#pragma unroll
    for (int off = 32; off; off >>= 1) a += __shfl_xor(a, off);
    if (lane == (s & 63)) { if (s < 64) e0 = a; else e1 = a; }
  }
  float m = fmaxf(e0, e1);
#pragma unroll
  for (int off = 32; off; off >>= 1) m = fmaxf(m, __shfl_xor(m, off));
  float p0 = __expf(e0 - m), p1 = __expf(e1 - m);
  float sum = p0 + p1;
#pragma unroll
  for (int off = 32; off; off >>= 1) sum += __shfl_xor(sum, off);
  float inv = 1.f / sum;
  float a0 = p0 * inv, a1 = p1 * inv;

  float ctx[8] = {0.f, 0.f, 0.f, 0.f, 0.f, 0.f, 0.f, 0.f};
  for (int s = 0; s < Ss; ++s) {
    float as = __shfl(s < 64 ? a0 : a1, s & 63);
    const float4* p = reinterpret_cast<const float4*>(&enc[(size_t)(b * Ss + s) * Dd + d0]);
    float4 x = p[0], y = p[1];
    ctx[0] += as * x.x; ctx[1] += as * x.y; ctx[2] += as * x.z; ctx[3] += as * x.w;
    ctx[4] += as * y.x; ctx[5] += as * y.y; ctx[6] += as * y.z; ctx[7] += as * y.w;
  }
  u16x8 co;
#pragma unroll
  for (int j = 0; j < 8; ++j) co[j] = f2bf(ctx[j]);
  size_t cbase = (size_t)(b * Tt + t) * (2 * Dd);
  *reinterpret_cast<u16x8*>(&cat[cbase + d0]) = co;
  u16x8 ov = *reinterpret_cast<const u16x8*>(&out_hi[(size_t)(b * Tt + t) * Dd + d0]);
  *reinterpret_cast<u16x8*>(&cat[cbase + Dd + d0]) = ov;
}

// ---------------- host ----------------
extern "C" void kernel_launch(void* const* d_in, const int* in_sizes, int n_in,
                              void* d_out, int out_size, void* d_ws, size_t ws_size,
                              hipStream_t stream) {
  const int* words = (const int*)d_in[0];
  const float* enc = (const float*)d_in[1];
  const float* pre_h = (const float*)d_in[2];
  const float* cell = (const float*)d_in[3];
  const float* emb = (const float*)d_in[4];
  const float* W_ih = (const float*)d_in[5];
  const float* W_hh = (const float*)d_in[6];
  const float* b_ih = (const float*)d_in[7];
  const float* b_hh = (const float*)d_in[8];
  const float* Wh_w = (const float*)d_in[9];
  const float* Ws_w = (const float*)d_in[10];
  const float* Ws_b = (const float*)d_in[11];
  const float* vt_w = (const float*)d_in[12];
  const float* V_w = (const float*)d_in[13];
  const float* V_b = (const float*)d_in[14];
  const float* Vp_w = (const float*)d_in[15];
  const float* Vp_b = (const float*)d_in[16];
  float* outp = (float*)d_out;

  char* ws = (char*)d_ws;
  size_t off = 0;
  auto alloc = [&](size_t bytes) {
    char* p = ws + off;
    off = (off + bytes + 255) & ~(size_t)255;
    return p;
  };
  int* flags = (int*)alloc(4096);                             // 32 x 128B lines
  float* xg = (float*)alloc((size_t)Bb * Tt * FD * 4);        // 8 MB
  float* wh = (float*)alloc((size_t)Bb * Ss * Dd * 4);        // 4 MB
  float* wst = (float*)alloc((size_t)Bb * Tt * Dd * 4);       // 2 MB
  unsigned* hpack = (unsigned*)alloc((size_t)(Tt + 1) * Bb * Dd * 4);
  u16* out_hi = (u16*)alloc((size_t)Bb * Tt * Dd * 2);
  u16* out_lo = (u16*)alloc((size_t)Bb * Tt * Dd * 2);
  u16* x_bf = (u16*)alloc((size_t)Bb * Tt * Dd * 2);
  u16* enc_hi = (u16*)alloc((size_t)Bb * Ss * Dd * 2);
  u16* enc_lo = (u16*)alloc((size_t)Bb * Ss * Dd * 2);
  u16* Wih_bf = (u16*)alloc((size_t)FD * Dd * 2);
  u16* Whw_hi = (u16*)alloc((size_t)Dd * Dd * 2);
  u16* Whw_lo = (u16*)alloc((size_t)Dd * Dd * 2);
  u16* Wsw_hi = (u16*)alloc((size_t)Dd * Dd * 2);
  u16* Wsw_lo = (u16*)alloc((size_t)Dd * Dd * 2);
  u16* Vw_bf = (u16*)alloc((size_t)Dd * 2 * Dd * 2);
  u16* Vp_bf = (u16*)alloc((size_t)Vv * Dd * 2);              // 32.8 MB
  u16* cat = (u16*)alloc((size_t)Bb * Tt * 2 * Dd * 2);
  u16* hmid = (u16*)alloc((size_t)Bb * Tt * Dd * 2);
  float* bsum = (float*)alloc((size_t)FD * 4);
  if (off > ws_size) return;  // workspace too small: fail cleanly

  hipMemsetAsync(flags, 0, 4096, stream);

  // fused prologue: embed + preh + bsum + (Wih, enc, Whw) converts
  k_pre<<<Bb * Tt + 40 + 256, 256, 0, stream>>>(words, emb, x_bf, pre_h, (unsigned*)hpack,
                                                b_ih, b_hh, bsum,
                                                W_ih, Wih_bf, enc, enc_hi, enc_lo,
                                                Wh_w, Whw_hi, Whw_lo);
  // xg = x @ W_ih^T + (b_ih + b_hh)   [1024, 2048]
  k_gemm<true, false, 1><<<8 * 16, 256, 0, stream>>>(x_bf, nullptr, Wih_bf, nullptr,
                                                     xg, nullptr, bsum, 1024, 2048, 512);
  // LSTM (blocks 0-31, R5 protocol) + side work: wh GEMM + Vp/V/Ws converts
  k_lstm_fused<<<256, 256, 0, stream>>>(xg, W_hh, cell, (unsigned*)hpack, out_hi, out_lo,
                                        flags, enc_hi, enc_lo, Whw_hi, Whw_lo, wh,
                                        Vp_w, Vp_bf, V_w, Vw_bf, Ws_w, Wsw_hi, Wsw_lo);
  // ws = out @ Ws_w^T + Ws_b (fused split 3-term)  [1024, 512]
  k_gemm<true, false, 3><<<8 * 4, 256, 0, stream>>>(out_hi, out_lo, Wsw_hi, Wsw_lo,
                                                    wst, nullptr, Ws_b, 1024, 512, 512);
  // fused attention -> cat = [context, out] bf16
  k_attn<<<256, 256, 0, stream>>>(wh, wst, vt_w, enc, out_hi, cat);
  // hmid = cat @ V_w^T + V_b -> bf16  [1024, 512]
  k_gemm<true, true, 1><<<8 * 4, 256, 0, stream>>>(cat, nullptr, Vw_bf, nullptr,
                                                   nullptr, hmid, V_b, 1024, 512, 1024);
  // logits = hmid @ Vp_w^T + Vp_b  [1024, 32000] — XCD-swizzled tiled GEMM
  k_logits_sw<<<2048, 256, 0, stream>>>(hmid, Vp_bf, Vp_b, outp);
}